// Round 20
// baseline (231.844 us; speedup 1.0000x reference)
//
#include <hip/hip_runtime.h>

// BlockSparseAttention B=2,H=16,N=2048,D=64 fp32, block-causal.
// R25 = R24 resubmitted byte-for-byte (acquisition timeout in R19; unmeasured).
// R24 = R23 (measured: ~58us dispatch, total 127.7 = session best; balanced
// {q,15-q} map verified) + prefetch depth 1->2 with write-at-top round order.
// R23 round: {barrier; load(i+1); proc(i); write(i+1)} -- write waits vmcnt on
// loads issued the SAME round (cover = proc ~0.5us < L3 lat 0.5-0.9us).
// R24 round: {barrier; write(i+1) [regs loaded last round, ZERO wait];
//             load(i+2); proc(i)} -- each tile's loads fly ~1.5 rounds.
// Staging sets: A=even tiles, B=odd. Steady-state liveness = ONE set (32 regs);
// prologue (load0;load1;write0) briefly has both (64) -> VGPR predicted 88-120;
// if 128 + WRITE>20MB => prologue spill => fallback: depth-2 for V only.
// Numerics bit-identical (same LDS images, same proc math, verified absmax).
// Model: solo-8-wave round ~3.3us; removing the ~0.3-0.6us vmcnt leg ->
// predicted dispatch 45-55us, total 112-122, WRITE 16.4MB, FETCH ~25MB.
// Failure reads: ~58 unchanged -> chain is ds_read+exp+barrier -> attack
// VALU/exp chain or 3-WG residency next; absmax -> impossible -> rerun.
//
// Design (verified): INTRA-WG SPLIT-K. 512-thread WGs, grid 512, map
// lo=wg&255,hi=wg>>8; qsub=hi?15-(lo>>4):lo>>4; bh=(lo&15)+(hi<<4).
// Waves 0-3 = key-group L, 4-7 = H; each group owns 2x16KB double buffer.
// Epilogue: H -> LDS partials (stride 41, conflict-free), L merges + writes O.

typedef short bf16x8 __attribute__((ext_vector_type(8)));
typedef float f32x4  __attribute__((ext_vector_type(4)));
typedef unsigned short u16;
typedef u16 u16x8 __attribute__((ext_vector_type(8)));

#define MFMA(A,B,C) __builtin_amdgcn_mfma_f32_16x16x32_bf16((A),(B),(C),0,0,0)

__device__ __forceinline__ u16 f2bf_rne(float f) {
    union { float f; unsigned u; } c; c.f = f;
    unsigned r = c.u + 0x7FFFu + ((c.u >> 16) & 1u);
    return (u16)(r >> 16);
}
__device__ __forceinline__ u16 f2bf_fast(float f) {
    union { float f; unsigned u; } c; c.f = f;
    return (u16)((c.u + 0x8000u) >> 16);
}

// ---- fused main: 512 WGs x 512 threads; 128 q-rows; 2 key-groups x 4 waves ----
__global__ __launch_bounds__(512, 2)
void bsattn_fused(const float* __restrict__ Q, const float* __restrict__ K,
                  const float* __restrict__ V, const float* __restrict__ SC,
                  const int* __restrict__ RS, const int* __restrict__ RE,
                  float* __restrict__ O)
{
    constexpr int N = 2048, D = 64;
    int wg = blockIdx.x;
    // balanced pairing: CU c hosts wg=c and wg=c+256 with qsub q and 15-q
    // -> per-CU tile-procs = w(q)+w(15-q) = 36 uniformly.
    int lo = wg & 255, hi = wg >> 8;
    int qs = lo >> 4;                     // [0,16)
    int qsub = hi ? (15 - qs) : qs;
    int bh   = (lo & 15) + (hi << 4);
    int q0 = qsub << 7;                   // 128-row q tile

    int tid = threadIdx.x;
    int grp = tid >> 8;                   // 0 = low-key group, 1 = high-key group
    int tl  = tid & 255;                  // group-local tid
    int wid = tl >> 6, lane = tl & 63;    // group-local wave, lane
    int n = lane & 15, g = lane >> 4;

    __shared__ __align__(16) u16 lsm[32768];   // 2 groups x 2 x 16KB tile buffers
    __shared__ int sbi[16];

    int row0 = q0 + wid * 32 + n;          // fragment A row (same rows both groups)
    int row1 = row0 + 16;                  // fragment B row
    int rs_l0 = RS[row0], re_l0 = RE[row0];
    int rs_l1 = RS[row1], re_l1 = RE[row1];
    int w_rs_min = min(rs_l0, rs_l1), w_rs_max = max(rs_l0, rs_l1);
    int w_re_min = min(re_l0, re_l1), w_re_max = max(re_l0, re_l1);
    #pragma unroll
    for (int o = 1; o < 16; o <<= 1) {
        w_rs_min = min(w_rs_min, __shfl_xor(w_rs_min, o));
        w_rs_max = max(w_rs_max, __shfl_xor(w_rs_max, o));
        w_re_min = min(w_re_min, __shfl_xor(w_re_min, o));
        w_re_max = max(w_re_max, __shfl_xor(w_re_max, o));
    }
    int wid8 = tid >> 6;                   // WG-wide wave id 0..7
    if (lane == 0) { sbi[wid8 * 2] = w_rs_min; sbi[wid8 * 2 + 1] = w_re_max; }

    float sscale = SC[0] * 1.44269504088896340736f;   // exp2 domain

    bf16x8 qA0, qA1, qB0, qB1;
    {
        const float* qp = Q + ((size_t)bh * N + row0) * D + g * 8;
        float4 a0 = *(const float4*)qp,        a1 = *(const float4*)(qp + 4);
        float4 b0 = *(const float4*)(qp + 32), b1 = *(const float4*)(qp + 36);
        qA0[0]=f2bf_rne(a0.x*sscale); qA0[1]=f2bf_rne(a0.y*sscale);
        qA0[2]=f2bf_rne(a0.z*sscale); qA0[3]=f2bf_rne(a0.w*sscale);
        qA0[4]=f2bf_rne(a1.x*sscale); qA0[5]=f2bf_rne(a1.y*sscale);
        qA0[6]=f2bf_rne(a1.z*sscale); qA0[7]=f2bf_rne(a1.w*sscale);
        qA1[0]=f2bf_rne(b0.x*sscale); qA1[1]=f2bf_rne(b0.y*sscale);
        qA1[2]=f2bf_rne(b0.z*sscale); qA1[3]=f2bf_rne(b0.w*sscale);
        qA1[4]=f2bf_rne(b1.x*sscale); qA1[5]=f2bf_rne(b1.y*sscale);
        qA1[6]=f2bf_rne(b1.z*sscale); qA1[7]=f2bf_rne(b1.w*sscale);
    }
    {
        const float* qp = Q + ((size_t)bh * N + row1) * D + g * 8;
        float4 a0 = *(const float4*)qp,        a1 = *(const float4*)(qp + 4);
        float4 b0 = *(const float4*)(qp + 32), b1 = *(const float4*)(qp + 36);
        qB0[0]=f2bf_rne(a0.x*sscale); qB0[1]=f2bf_rne(a0.y*sscale);
        qB0[2]=f2bf_rne(a0.z*sscale); qB0[3]=f2bf_rne(a0.w*sscale);
        qB0[4]=f2bf_rne(a1.x*sscale); qB0[5]=f2bf_rne(a1.y*sscale);
        qB0[6]=f2bf_rne(a1.z*sscale); qB0[7]=f2bf_rne(a1.w*sscale);
        qB1[0]=f2bf_rne(b0.x*sscale); qB1[1]=f2bf_rne(b0.y*sscale);
        qB1[2]=f2bf_rne(b0.z*sscale); qB1[3]=f2bf_rne(b0.w*sscale);
        qB1[4]=f2bf_rne(b1.x*sscale); qB1[5]=f2bf_rne(b1.y*sscale);
        qB1[6]=f2bf_rne(b1.z*sscale); qB1[7]=f2bf_rne(b1.w*sscale);
    }

    __syncthreads();
    int kst  = min(min(min(sbi[0], sbi[2]),  min(sbi[4],  sbi[6])),
                   min(min(sbi[8], sbi[10]), min(sbi[12], sbi[14]))) & ~63;
    int kend = max(max(max(sbi[1], sbi[3]),  max(sbi[5],  sbi[7])),
                   max(max(sbi[9], sbi[11]), max(sbi[13], sbi[15])));
    int t0 = kst >> 6;
    int w  = (kend - kst + 63) >> 6;       // multiple of 4 (256-blocks)
    int wl = w >> 1;                       // per-group trip count (>=2), WG-uniform

    // loop-invariant LDS read offsets (u16 indices; verified images)
    int rA   = ((n >> 2) << 3) + (n & 3);
    int phk  = (n & 3) + 4 * ((n >> 2) & 1);
    int osA0 = rA * 64 + ((g + phk) & 7) * 8;
    int osA1 = rA * 64 + ((g + 4 + phk) & 7) * 8;
    int ov0  = 4096 + n * 64 + ((    g + (n & 7)) & 7) * 8;
    int ov1  = 4096 + n * 64 + ((4 + g + (n & 7)) & 7) * 8;

    // loop-invariant STAGING coords (formulas identical to the verified prep kernel)
    int key_l = tl >> 2, c2 = (tl & 3) << 1;                   // K: thread -> (key, dim-chunk)
    int rotb  = (key_l & 3) + 4 * ((key_l >> 3) & 1);
    int kiA   = key_l * 64 + (((c2    ) + rotb) & 7) * 8;
    int kiB   = key_l * 64 + (((c2 + 1) + rotb) & 7) * 8;
    int kc    = lane >> 3, kw = lane & 7;                      // V: thread -> (key=lane, dims wid*16..)
    const float* Kb = K + (size_t)bh * N * D;
    const float* Vb = V + (size_t)bh * N * D;

    int go = grp << 14;                    // group LDS base (16384 u16 = 2 buffers)

    f32x4 accA[4], accB[4];
    f32x4 acclA = {0.f,0.f,0.f,0.f}, acclB = {0.f,0.f,0.f,0.f};
    #pragma unroll
    for (int c = 0; c < 4; ++c) {
        accA[c] = (f32x4){0.f,0.f,0.f,0.f};
        accB[c] = (f32x4){0.f,0.f,0.f,0.f};
    }
    bf16x8 ones;
    #pragma unroll
    for (int j = 0; j < 8; ++j) ones[j] = (short)0x3F80;

    // TWO staging register sets: set A = even tiles, set B = odd tiles.
    // Exactly one set is live through proc (other dies at write-at-top).
    float4 kA0, kA1, kA2, kA3, vA0, vA1, vA2, vA3;
    float4 kB0, kB1, kB2, kB3, vB0, vB1, vB2, vB3;

    auto stage_load = [&](int t) {          // issue f32 loads for group tile t
        if (t < wl) {
            int tile = t0 + grp * wl + t;
            const float* kp = Kb + (size_t)tile * 4096 + key_l * 64 + c2 * 8;
            const float* vp = Vb + (size_t)tile * 4096 + lane * 64 + wid * 16;
            if (t & 1) {
                kB0 = *(const float4*)kp;       kB1 = *(const float4*)(kp + 4);
                kB2 = *(const float4*)(kp + 8); kB3 = *(const float4*)(kp + 12);
                vB0 = *(const float4*)vp;       vB1 = *(const float4*)(vp + 4);
                vB2 = *(const float4*)(vp + 8); vB3 = *(const float4*)(vp + 12);
            } else {
                kA0 = *(const float4*)kp;       kA1 = *(const float4*)(kp + 4);
                kA2 = *(const float4*)(kp + 8); kA3 = *(const float4*)(kp + 12);
                vA0 = *(const float4*)vp;       vA1 = *(const float4*)(vp + 4);
                vA2 = *(const float4*)(vp + 8); vA3 = *(const float4*)(vp + 12);
            }
        }
    };
    auto stage_write = [&](int t) {         // cvt + swizzled LDS image write
        if (t < wl) {
            u16* dst = &lsm[go + ((t & 1) << 13)];
            float4 k0, k1, k2, k3, v0, v1, v2, v3;
            if (t & 1) { k0=kB0; k1=kB1; k2=kB2; k3=kB3; v0=vB0; v1=vB1; v2=vB2; v3=vB3; }
            else       { k0=kA0; k1=kA1; k2=kA2; k3=kA3; v0=vA0; v1=vA1; v2=vA2; v3=vA3; }
            u16x8 a, b;
            a[0]=f2bf_rne(k0.x); a[1]=f2bf_rne(k0.y); a[2]=f2bf_rne(k0.z); a[3]=f2bf_rne(k0.w);
            a[4]=f2bf_rne(k1.x); a[5]=f2bf_rne(k1.y); a[6]=f2bf_rne(k1.z); a[7]=f2bf_rne(k1.w);
            b[0]=f2bf_rne(k2.x); b[1]=f2bf_rne(k2.y); b[2]=f2bf_rne(k2.z); b[3]=f2bf_rne(k2.w);
            b[4]=f2bf_rne(k3.x); b[5]=f2bf_rne(k3.y); b[6]=f2bf_rne(k3.z); b[7]=f2bf_rne(k3.w);
            *(u16x8*)&dst[kiA] = a;
            *(u16x8*)&dst[kiB] = b;
            float vy[16] = { v0.x,v0.y,v0.z,v0.w, v1.x,v1.y,v1.z,v1.w,
                             v2.x,v2.y,v2.z,v2.w, v3.x,v3.y,v3.z,v3.w };
            #pragma unroll
            for (int j = 0; j < 16; ++j) {
                int d = wid * 16 + j;
                dst[4096 + d * 64 + ((kc + (j & 7)) & 7) * 8 + kw] = f2bf_rne(vy[j]);
            }
        }
    };

    auto proc = [&](int kb, const u16* ls) {
        bool bdry = (kb < w_rs_max) || (kb + 64 > w_re_min);   // wave-uniform
        #pragma unroll
        for (int h = 0; h < 2; ++h) {
            int hb = h * 2048;
            bf16x8 k00 = *(const bf16x8*)&ls[hb + osA0];
            bf16x8 k01 = *(const bf16x8*)&ls[hb + osA1];
            bf16x8 k10 = *(const bf16x8*)&ls[hb + osA0 + 256];
            bf16x8 k11 = *(const bf16x8*)&ls[hb + osA1 + 256];
            f32x4 tA0 = {0.f,0.f,0.f,0.f}, tA1 = tA0, tB0 = tA0, tB1 = tA0;
            __builtin_amdgcn_s_setprio(1);
            tA0 = MFMA(k00, qA0, tA0); tA0 = MFMA(k01, qA1, tA0);
            tA1 = MFMA(k10, qA0, tA1); tA1 = MFMA(k11, qA1, tA1);
            tB0 = MFMA(k00, qB0, tB0); tB0 = MFMA(k01, qB1, tB0);
            tB1 = MFMA(k10, qB0, tB1); tB1 = MFMA(k11, qB1, tB1);
            __builtin_amdgcn_s_setprio(0);
            float sA[8], sB[8];
            #pragma unroll
            for (int r = 0; r < 4; ++r) {
                sA[r] = tA0[r]; sA[4 + r] = tA1[r];
                sB[r] = tB0[r]; sB[4 + r] = tB1[r];
            }
            if (bdry) {
                #pragma unroll
                for (int j = 0; j < 8; ++j) {
                    int key = kb + h * 32 + g * 8 + j;
                    if (key < rs_l0 || key >= re_l0) sA[j] = -1e30f;
                    if (key < rs_l1 || key >= re_l1) sB[j] = -1e30f;
                }
            }
            bf16x8 pA, pB;
            #pragma unroll
            for (int j = 0; j < 8; ++j) { float p = __builtin_amdgcn_exp2f(sA[j]); pA[j] = (short)f2bf_fast(p); }
            #pragma unroll
            for (int j = 0; j < 8; ++j) { float p = __builtin_amdgcn_exp2f(sB[j]); pB[j] = (short)f2bf_fast(p); }
            int ov = h ? ov1 : ov0;
            bf16x8 v0 = *(const bf16x8*)&ls[ov       ];
            bf16x8 v1 = *(const bf16x8*)&ls[ov + 1024];
            bf16x8 v2 = *(const bf16x8*)&ls[ov + 2048];
            bf16x8 v3 = *(const bf16x8*)&ls[ov + 3072];
            __builtin_amdgcn_s_setprio(1);
            accA[0] = MFMA(pA, v0, accA[0]);
            accA[1] = MFMA(pA, v1, accA[1]);
            accA[2] = MFMA(pA, v2, accA[2]);
            accA[3] = MFMA(pA, v3, accA[3]);
            acclA   = MFMA(pA, ones, acclA);
            accB[0] = MFMA(pB, v0, accB[0]);
            accB[1] = MFMA(pB, v1, accB[1]);
            accB[2] = MFMA(pB, v2, accB[2]);
            accB[3] = MFMA(pB, v3, accB[3]);
            acclB   = MFMA(pB, ones, acclB);
            __builtin_amdgcn_s_setprio(0);
        }
    };

    // prologue: tiles 0,1 loads in flight; write(0) waits only on set A
    stage_load(0);
    stage_load(1);
    stage_write(0);
    for (int i = 0; i < wl; ++i) {
        __syncthreads();          // buf[i&1] ready; drains in-flight loads to regs
        stage_write(i + 1);       // regs loaded >=1 round ago -> zero wait
        stage_load(i + 2);        // ~1.5 rounds of flight before its write
        proc(kst + ((grp * wl + i) << 6), &lsm[go + ((i & 1) << 13)]);
    }

    // ---- merge: group H -> LDS, group L sums + normalizes + writes O ----
    __syncthreads();                        // all procs done; lsm reusable
    float* mf = (float*)lsm;                // 16384 f32 capacity; need <= 10495
    if (grp == 1) {
        int slot = tl * 41;                 // bank = (9*lane+c)%32, gcd(9,32)=1 -> conflict-free
        #pragma unroll
        for (int c = 0; c < 4; ++c)
            #pragma unroll
            for (int r = 0; r < 4; ++r) mf[slot + c * 4 + r] = accA[c][r];
        #pragma unroll
        for (int r = 0; r < 4; ++r) mf[slot + 16 + r] = acclA[r];
        #pragma unroll
        for (int c = 0; c < 4; ++c)
            #pragma unroll
            for (int r = 0; r < 4; ++r) mf[slot + 20 + c * 4 + r] = accB[c][r];
        #pragma unroll
        for (int r = 0; r < 4; ++r) mf[slot + 36 + r] = acclB[r];
    }
    __syncthreads();
    if (grp == 0) {
        int slot = tl * 41;
        #pragma unroll
        for (int c = 0; c < 4; ++c)
            #pragma unroll
            for (int r = 0; r < 4; ++r) accA[c][r] += mf[slot + c * 4 + r];
        #pragma unroll
        for (int r = 0; r < 4; ++r) acclA[r] += mf[slot + 16 + r];
        #pragma unroll
        for (int c = 0; c < 4; ++c)
            #pragma unroll
            for (int r = 0; r < 4; ++r) accB[c][r] += mf[slot + 20 + c * 4 + r];
        #pragma unroll
        for (int r = 0; r < 4; ++r) acclB[r] += mf[slot + 36 + r];

        // epilogue: frag A rows q0+wid*32+4g+r, frag B rows +16; cols 16c+n
        int rb = g << 2;
        {
            int orow = q0 + wid * 32 + rb;
            float* ob = O + ((size_t)bh * N + orow) * D + n;
            #pragma unroll
            for (int r = 0; r < 4; ++r) {
                float li = 1.0f / acclA[r];
                float* rp = ob + (size_t)r * D;
                rp[0]  = accA[0][r] * li;
                rp[16] = accA[1][r] * li;
                rp[32] = accA[2][r] * li;
                rp[48] = accA[3][r] * li;
            }
        }
        {
            int orow = q0 + wid * 32 + 16 + rb;
            float* ob = O + ((size_t)bh * N + orow) * D + n;
            #pragma unroll
            for (int r = 0; r < 4; ++r) {
                float li = 1.0f / acclB[r];
                float* rp = ob + (size_t)r * D;
                rp[0]  = accB[0][r] * li;
                rp[16] = accB[1][r] * li;
                rp[32] = accB[2][r] * li;
                rp[48] = accB[3][r] * li;
            }
        }
    }
}

extern "C" void kernel_launch(void* const* d_in, const int* in_sizes, int n_in,
                              void* d_out, int out_size, void* d_ws, size_t ws_size,
                              hipStream_t stream) {
    const float* q  = (const float*)d_in[0];
    const float* k  = (const float*)d_in[1];
    const float* v  = (const float*)d_in[2];
    const float* sc = (const float*)d_in[3];
    const int* rs   = (const int*)d_in[4];
    const int* re   = (const int*)d_in[5];
    float* out      = (float*)d_out;

    bsattn_fused<<<dim3(512), dim3(512), 0, stream>>>(q, k, v, sc, rs, re, out);
}

// Round 21
// 135.210 us; speedup vs baseline: 1.7147x; 1.7147x over previous
//
#include <hip/hip_runtime.h>

// BlockSparseAttention B=2,H=16,N=2048,D=64 fp32, block-causal.
// R26 = R24's depth-2 prefetch REDONE with STATIC set parity (rule-#20 fix).
// R24/R25 post-mortem (measured): dispatch 153us, WRITE 307MB, FETCH 176MB,
// VGPR 80 -- the `if (t&1)` runtime-parity set selection put both staging sets
// in SCRATCH (runtime-indexed reg arrays -> local memory). ~480MB of spill
// traffic at 3.2TB/s = the whole regression. Fix per the documented rule:
// explicit 2x loop unroll so every set reference is compile-time static.
// wl is ALWAYS EVEN (w in {4,8,...,32} -> wl in {2,...,16}) -> no tail.
// Liveness: writeA kills set A before loadB refills set B (and vice versa)
// -> exactly ONE 32-reg set live at a time -> VGPR ~100-115 < 128 budget.
// Numerics bit-identical to R23 (measured best: ~58us dispatch, 127.7 total).
// Pipeline: {barrier; writeB(i+1)[regs landed, zero wait]; loadA(i+2);
//            proc(i,buf0); barrier; writeA(i+2); loadB(i+3); proc(i+1,buf1)}.
// Predicted: WRITE 16.4MB, FETCH ~25MB, VGPR 90-118, dispatch 45-55us,
// total 112-122us. Failure: WRITE>20MB -> still scratched -> revert R23;
// dispatch ~58 clean -> vmcnt not on chain -> attack VALU/residency next.
//
// Design (verified): INTRA-WG SPLIT-K. 512-thread WGs, grid 512, map
// lo=wg&255,hi=wg>>8; qsub=hi?15-(lo>>4):lo>>4; bh=(lo&15)+(hi<<4)
// (balanced {q,15-q}: every CU gets exactly 36 tile-procs).
// Waves 0-3 = key-group L, 4-7 = H; each group owns 2x16KB double buffer.
// Epilogue: H -> LDS partials (stride 41, conflict-free), L merges + writes O.

typedef short bf16x8 __attribute__((ext_vector_type(8)));
typedef float f32x4  __attribute__((ext_vector_type(4)));
typedef unsigned short u16;
typedef u16 u16x8 __attribute__((ext_vector_type(8)));

#define MFMA(A,B,C) __builtin_amdgcn_mfma_f32_16x16x32_bf16((A),(B),(C),0,0,0)

__device__ __forceinline__ u16 f2bf_rne(float f) {
    union { float f; unsigned u; } c; c.f = f;
    unsigned r = c.u + 0x7FFFu + ((c.u >> 16) & 1u);
    return (u16)(r >> 16);
}
__device__ __forceinline__ u16 f2bf_fast(float f) {
    union { float f; unsigned u; } c; c.f = f;
    return (u16)((c.u + 0x8000u) >> 16);
}

// ---- fused main: 512 WGs x 512 threads; 128 q-rows; 2 key-groups x 4 waves ----
__global__ __launch_bounds__(512, 2)
void bsattn_fused(const float* __restrict__ Q, const float* __restrict__ K,
                  const float* __restrict__ V, const float* __restrict__ SC,
                  const int* __restrict__ RS, const int* __restrict__ RE,
                  float* __restrict__ O)
{
    constexpr int N = 2048, D = 64;
    int wg = blockIdx.x;
    int lo = wg & 255, hi = wg >> 8;
    int qs = lo >> 4;                     // [0,16)
    int qsub = hi ? (15 - qs) : qs;
    int bh   = (lo & 15) + (hi << 4);
    int q0 = qsub << 7;                   // 128-row q tile

    int tid = threadIdx.x;
    int grp = tid >> 8;                   // 0 = low-key group, 1 = high-key group
    int tl  = tid & 255;                  // group-local tid
    int wid = tl >> 6, lane = tl & 63;    // group-local wave, lane
    int n = lane & 15, g = lane >> 4;

    __shared__ __align__(16) u16 lsm[32768];   // 2 groups x 2 x 16KB tile buffers
    __shared__ int sbi[16];

    int row0 = q0 + wid * 32 + n;          // fragment A row (same rows both groups)
    int row1 = row0 + 16;                  // fragment B row
    int rs_l0 = RS[row0], re_l0 = RE[row0];
    int rs_l1 = RS[row1], re_l1 = RE[row1];
    int w_rs_min = min(rs_l0, rs_l1), w_rs_max = max(rs_l0, rs_l1);
    int w_re_min = min(re_l0, re_l1), w_re_max = max(re_l0, re_l1);
    #pragma unroll
    for (int o = 1; o < 16; o <<= 1) {
        w_rs_min = min(w_rs_min, __shfl_xor(w_rs_min, o));
        w_rs_max = max(w_rs_max, __shfl_xor(w_rs_max, o));
        w_re_min = min(w_re_min, __shfl_xor(w_re_min, o));
        w_re_max = max(w_re_max, __shfl_xor(w_re_max, o));
    }
    int wid8 = tid >> 6;                   // WG-wide wave id 0..7
    if (lane == 0) { sbi[wid8 * 2] = w_rs_min; sbi[wid8 * 2 + 1] = w_re_max; }

    float sscale = SC[0] * 1.44269504088896340736f;   // exp2 domain

    bf16x8 qA0, qA1, qB0, qB1;
    {
        const float* qp = Q + ((size_t)bh * N + row0) * D + g * 8;
        float4 a0 = *(const float4*)qp,        a1 = *(const float4*)(qp + 4);
        float4 b0 = *(const float4*)(qp + 32), b1 = *(const float4*)(qp + 36);
        qA0[0]=f2bf_rne(a0.x*sscale); qA0[1]=f2bf_rne(a0.y*sscale);
        qA0[2]=f2bf_rne(a0.z*sscale); qA0[3]=f2bf_rne(a0.w*sscale);
        qA0[4]=f2bf_rne(a1.x*sscale); qA0[5]=f2bf_rne(a1.y*sscale);
        qA0[6]=f2bf_rne(a1.z*sscale); qA0[7]=f2bf_rne(a1.w*sscale);
        qA1[0]=f2bf_rne(b0.x*sscale); qA1[1]=f2bf_rne(b0.y*sscale);
        qA1[2]=f2bf_rne(b0.z*sscale); qA1[3]=f2bf_rne(b0.w*sscale);
        qA1[4]=f2bf_rne(b1.x*sscale); qA1[5]=f2bf_rne(b1.y*sscale);
        qA1[6]=f2bf_rne(b1.z*sscale); qA1[7]=f2bf_rne(b1.w*sscale);
    }
    {
        const float* qp = Q + ((size_t)bh * N + row1) * D + g * 8;
        float4 a0 = *(const float4*)qp,        a1 = *(const float4*)(qp + 4);
        float4 b0 = *(const float4*)(qp + 32), b1 = *(const float4*)(qp + 36);
        qB0[0]=f2bf_rne(a0.x*sscale); qB0[1]=f2bf_rne(a0.y*sscale);
        qB0[2]=f2bf_rne(a0.z*sscale); qB0[3]=f2bf_rne(a0.w*sscale);
        qB0[4]=f2bf_rne(a1.x*sscale); qB0[5]=f2bf_rne(a1.y*sscale);
        qB0[6]=f2bf_rne(a1.z*sscale); qB0[7]=f2bf_rne(a1.w*sscale);
        qB1[0]=f2bf_rne(b0.x*sscale); qB1[1]=f2bf_rne(b0.y*sscale);
        qB1[2]=f2bf_rne(b0.z*sscale); qB1[3]=f2bf_rne(b0.w*sscale);
        qB1[4]=f2bf_rne(b1.x*sscale); qB1[5]=f2bf_rne(b1.y*sscale);
        qB1[6]=f2bf_rne(b1.z*sscale); qB1[7]=f2bf_rne(b1.w*sscale);
    }

    __syncthreads();
    int kst  = min(min(min(sbi[0], sbi[2]),  min(sbi[4],  sbi[6])),
                   min(min(sbi[8], sbi[10]), min(sbi[12], sbi[14]))) & ~63;
    int kend = max(max(max(sbi[1], sbi[3]),  max(sbi[5],  sbi[7])),
                   max(max(sbi[9], sbi[11]), max(sbi[13], sbi[15])));
    int t0 = kst >> 6;
    int w  = (kend - kst + 63) >> 6;       // multiple of 4 (256-blocks)
    int wl = w >> 1;                       // per-group trips; ALWAYS EVEN (>=2)

    // loop-invariant LDS read offsets (u16 indices; verified images)
    int rA   = ((n >> 2) << 3) + (n & 3);
    int phk  = (n & 3) + 4 * ((n >> 2) & 1);
    int osA0 = rA * 64 + ((g + phk) & 7) * 8;
    int osA1 = rA * 64 + ((g + 4 + phk) & 7) * 8;
    int ov0  = 4096 + n * 64 + ((    g + (n & 7)) & 7) * 8;
    int ov1  = 4096 + n * 64 + ((4 + g + (n & 7)) & 7) * 8;

    // loop-invariant STAGING coords (formulas identical to the verified prep kernel)
    int key_l = tl >> 2, c2 = (tl & 3) << 1;                   // K: thread -> (key, dim-chunk)
    int rotb  = (key_l & 3) + 4 * ((key_l >> 3) & 1);
    int kiA   = key_l * 64 + (((c2    ) + rotb) & 7) * 8;
    int kiB   = key_l * 64 + (((c2 + 1) + rotb) & 7) * 8;
    int kc    = lane >> 3, kw = lane & 7;                      // V: thread -> (key=lane, dims wid*16..)
    const float* Kb = K + (size_t)bh * N * D;
    const float* Vb = V + (size_t)bh * N * D;

    int go = grp << 14;                    // group LDS base (16384 u16 = 2 buffers)

    f32x4 accA[4], accB[4];
    f32x4 acclA = {0.f,0.f,0.f,0.f}, acclB = {0.f,0.f,0.f,0.f};
    #pragma unroll
    for (int c = 0; c < 4; ++c) {
        accA[c] = (f32x4){0.f,0.f,0.f,0.f};
        accB[c] = (f32x4){0.f,0.f,0.f,0.f};
    }
    bf16x8 ones;
    #pragma unroll
    for (int j = 0; j < 8; ++j) ones[j] = (short)0x3F80;

    // TWO staging register sets, STATICALLY referenced (rule-#20 safe):
    // set A = even tiles -> buf0, set B = odd tiles -> buf1.
    float4 kA0, kA1, kA2, kA3, vA0, vA1, vA2, vA3;
    float4 kB0, kB1, kB2, kB3, vB0, vB1, vB2, vB3;

    auto stage_loadA = [&](int t) {
        if (t < wl) {
            int tile = t0 + grp * wl + t;
            const float* kp = Kb + (size_t)tile * 4096 + key_l * 64 + c2 * 8;
            const float* vp = Vb + (size_t)tile * 4096 + lane * 64 + wid * 16;
            kA0 = *(const float4*)kp;       kA1 = *(const float4*)(kp + 4);
            kA2 = *(const float4*)(kp + 8); kA3 = *(const float4*)(kp + 12);
            vA0 = *(const float4*)vp;       vA1 = *(const float4*)(vp + 4);
            vA2 = *(const float4*)(vp + 8); vA3 = *(const float4*)(vp + 12);
        }
    };
    auto stage_loadB = [&](int t) {
        if (t < wl) {
            int tile = t0 + grp * wl + t;
            const float* kp = Kb + (size_t)tile * 4096 + key_l * 64 + c2 * 8;
            const float* vp = Vb + (size_t)tile * 4096 + lane * 64 + wid * 16;
            kB0 = *(const float4*)kp;       kB1 = *(const float4*)(kp + 4);
            kB2 = *(const float4*)(kp + 8); kB3 = *(const float4*)(kp + 12);
            vB0 = *(const float4*)vp;       vB1 = *(const float4*)(vp + 4);
            vB2 = *(const float4*)(vp + 8); vB3 = *(const float4*)(vp + 12);
        }
    };
    auto stage_writeA = [&](int t) {        // even tile -> buf0
        if (t < wl) {
            u16* dst = &lsm[go];
            u16x8 a, b;
            a[0]=f2bf_rne(kA0.x); a[1]=f2bf_rne(kA0.y); a[2]=f2bf_rne(kA0.z); a[3]=f2bf_rne(kA0.w);
            a[4]=f2bf_rne(kA1.x); a[5]=f2bf_rne(kA1.y); a[6]=f2bf_rne(kA1.z); a[7]=f2bf_rne(kA1.w);
            b[0]=f2bf_rne(kA2.x); b[1]=f2bf_rne(kA2.y); b[2]=f2bf_rne(kA2.z); b[3]=f2bf_rne(kA2.w);
            b[4]=f2bf_rne(kA3.x); b[5]=f2bf_rne(kA3.y); b[6]=f2bf_rne(kA3.z); b[7]=f2bf_rne(kA3.w);
            *(u16x8*)&dst[kiA] = a;
            *(u16x8*)&dst[kiB] = b;
            float vy[16] = { vA0.x,vA0.y,vA0.z,vA0.w, vA1.x,vA1.y,vA1.z,vA1.w,
                             vA2.x,vA2.y,vA2.z,vA2.w, vA3.x,vA3.y,vA3.z,vA3.w };
            #pragma unroll
            for (int j = 0; j < 16; ++j) {
                int d = wid * 16 + j;
                dst[4096 + d * 64 + ((kc + (j & 7)) & 7) * 8 + kw] = f2bf_rne(vy[j]);
            }
        }
    };
    auto stage_writeB = [&](int t) {        // odd tile -> buf1
        if (t < wl) {
            u16* dst = &lsm[go + 8192];
            u16x8 a, b;
            a[0]=f2bf_rne(kB0.x); a[1]=f2bf_rne(kB0.y); a[2]=f2bf_rne(kB0.z); a[3]=f2bf_rne(kB0.w);
            a[4]=f2bf_rne(kB1.x); a[5]=f2bf_rne(kB1.y); a[6]=f2bf_rne(kB1.z); a[7]=f2bf_rne(kB1.w);
            b[0]=f2bf_rne(kB2.x); b[1]=f2bf_rne(kB2.y); b[2]=f2bf_rne(kB2.z); b[3]=f2bf_rne(kB2.w);
            b[4]=f2bf_rne(kB3.x); b[5]=f2bf_rne(kB3.y); b[6]=f2bf_rne(kB3.z); b[7]=f2bf_rne(kB3.w);
            *(u16x8*)&dst[kiA] = a;
            *(u16x8*)&dst[kiB] = b;
            float vy[16] = { vB0.x,vB0.y,vB0.z,vB0.w, vB1.x,vB1.y,vB1.z,vB1.w,
                             vB2.x,vB2.y,vB2.z,vB2.w, vB3.x,vB3.y,vB3.z,vB3.w };
            #pragma unroll
            for (int j = 0; j < 16; ++j) {
                int d = wid * 16 + j;
                dst[4096 + d * 64 + ((kc + (j & 7)) & 7) * 8 + kw] = f2bf_rne(vy[j]);
            }
        }
    };

    auto proc = [&](int kb, const u16* ls) {
        bool bdry = (kb < w_rs_max) || (kb + 64 > w_re_min);   // wave-uniform
        #pragma unroll
        for (int h = 0; h < 2; ++h) {
            int hb = h * 2048;
            bf16x8 k00 = *(const bf16x8*)&ls[hb + osA0];
            bf16x8 k01 = *(const bf16x8*)&ls[hb + osA1];
            bf16x8 k10 = *(const bf16x8*)&ls[hb + osA0 + 256];
            bf16x8 k11 = *(const bf16x8*)&ls[hb + osA1 + 256];
            f32x4 tA0 = {0.f,0.f,0.f,0.f}, tA1 = tA0, tB0 = tA0, tB1 = tA0;
            __builtin_amdgcn_s_setprio(1);
            tA0 = MFMA(k00, qA0, tA0); tA0 = MFMA(k01, qA1, tA0);
            tA1 = MFMA(k10, qA0, tA1); tA1 = MFMA(k11, qA1, tA1);
            tB0 = MFMA(k00, qB0, tB0); tB0 = MFMA(k01, qB1, tB0);
            tB1 = MFMA(k10, qB0, tB1); tB1 = MFMA(k11, qB1, tB1);
            __builtin_amdgcn_s_setprio(0);
            float sA[8], sB[8];
            #pragma unroll
            for (int r = 0; r < 4; ++r) {
                sA[r] = tA0[r]; sA[4 + r] = tA1[r];
                sB[r] = tB0[r]; sB[4 + r] = tB1[r];
            }
            if (bdry) {
                #pragma unroll
                for (int j = 0; j < 8; ++j) {
                    int key = kb + h * 32 + g * 8 + j;
                    if (key < rs_l0 || key >= re_l0) sA[j] = -1e30f;
                    if (key < rs_l1 || key >= re_l1) sB[j] = -1e30f;
                }
            }
            bf16x8 pA, pB;
            #pragma unroll
            for (int j = 0; j < 8; ++j) { float p = __builtin_amdgcn_exp2f(sA[j]); pA[j] = (short)f2bf_fast(p); }
            #pragma unroll
            for (int j = 0; j < 8; ++j) { float p = __builtin_amdgcn_exp2f(sB[j]); pB[j] = (short)f2bf_fast(p); }
            int ov = h ? ov1 : ov0;
            bf16x8 v0 = *(const bf16x8*)&ls[ov       ];
            bf16x8 v1 = *(const bf16x8*)&ls[ov + 1024];
            bf16x8 v2 = *(const bf16x8*)&ls[ov + 2048];
            bf16x8 v3 = *(const bf16x8*)&ls[ov + 3072];
            __builtin_amdgcn_s_setprio(1);
            accA[0] = MFMA(pA, v0, accA[0]);
            accA[1] = MFMA(pA, v1, accA[1]);
            accA[2] = MFMA(pA, v2, accA[2]);
            accA[3] = MFMA(pA, v3, accA[3]);
            acclA   = MFMA(pA, ones, acclA);
            accB[0] = MFMA(pB, v0, accB[0]);
            accB[1] = MFMA(pB, v1, accB[1]);
            accB[2] = MFMA(pB, v2, accB[2]);
            accB[3] = MFMA(pB, v3, accB[3]);
            acclB   = MFMA(pB, ones, acclB);
            __builtin_amdgcn_s_setprio(0);
        }
    };

    // prologue: tiles 0 (set A) and 1 (set B) in flight; write tile 0
    stage_loadA(0);
    stage_loadB(1);
    stage_writeA(0);
    for (int i = 0; i < wl; i += 2) {       // wl even -> no tail
        __syncthreads();                    // buf0 ready; drains in-flight loads
        stage_writeB(i + 1);                // set B regs landed -> zero wait
        stage_loadA(i + 2);                 // set A free (written above/last half)
        proc(kst + ((grp * wl + i) << 6), &lsm[go]);
        __syncthreads();                    // buf1 ready
        stage_writeA(i + 2);                // set A regs landed -> zero wait
        stage_loadB(i + 3);                 // set B free
        proc(kst + ((grp * wl + i + 1) << 6), &lsm[go + 8192]);
    }

    // ---- merge: group H -> LDS, group L sums + normalizes + writes O ----
    __syncthreads();                        // all procs done; lsm reusable
    float* mf = (float*)lsm;                // 16384 f32 capacity; need <= 10495
    if (grp == 1) {
        int slot = tl * 41;                 // bank = (9*lane+c)%32, gcd(9,32)=1 -> conflict-free
        #pragma unroll
        for (int c = 0; c < 4; ++c)
            #pragma unroll
            for (int r = 0; r < 4; ++r) mf[slot + c * 4 + r] = accA[c][r];
        #pragma unroll
        for (int r = 0; r < 4; ++r) mf[slot + 16 + r] = acclA[r];
        #pragma unroll
        for (int c = 0; c < 4; ++c)
            #pragma unroll
            for (int r = 0; r < 4; ++r) mf[slot + 20 + c * 4 + r] = accB[c][r];
        #pragma unroll
        for (int r = 0; r < 4; ++r) mf[slot + 36 + r] = acclB[r];
    }
    __syncthreads();
    if (grp == 0) {
        int slot = tl * 41;
        #pragma unroll
        for (int c = 0; c < 4; ++c)
            #pragma unroll
            for (int r = 0; r < 4; ++r) accA[c][r] += mf[slot + c * 4 + r];
        #pragma unroll
        for (int r = 0; r < 4; ++r) acclA[r] += mf[slot + 16 + r];
        #pragma unroll
        for (int c = 0; c < 4; ++c)
            #pragma unroll
            for (int r = 0; r < 4; ++r) accB[c][r] += mf[slot + 20 + c * 4 + r];
        #pragma unroll
        for (int r = 0; r < 4; ++r) acclB[r] += mf[slot + 36 + r];

        // epilogue: frag A rows q0+wid*32+4g+r, frag B rows +16; cols 16c+n
        int rb = g << 2;
        {
            int orow = q0 + wid * 32 + rb;
            float* ob = O + ((size_t)bh * N + orow) * D + n;
            #pragma unroll
            for (int r = 0; r < 4; ++r) {
                float li = 1.0f / acclA[r];
                float* rp = ob + (size_t)r * D;
                rp[0]  = accA[0][r] * li;
                rp[16] = accA[1][r] * li;
                rp[32] = accA[2][r] * li;
                rp[48] = accA[3][r] * li;
            }
        }
        {
            int orow = q0 + wid * 32 + 16 + rb;
            float* ob = O + ((size_t)bh * N + orow) * D + n;
            #pragma unroll
            for (int r = 0; r < 4; ++r) {
                float li = 1.0f / acclB[r];
                float* rp = ob + (size_t)r * D;
                rp[0]  = accB[0][r] * li;
                rp[16] = accB[1][r] * li;
                rp[32] = accB[2][r] * li;
                rp[48] = accB[3][r] * li;
            }
        }
    }
}

extern "C" void kernel_launch(void* const* d_in, const int* in_sizes, int n_in,
                              void* d_out, int out_size, void* d_ws, size_t ws_size,
                              hipStream_t stream) {
    const float* q  = (const float*)d_in[0];
    const float* k  = (const float*)d_in[1];
    const float* v  = (const float*)d_in[2];
    const float* sc = (const float*)d_in[3];
    const int* rs   = (const int*)d_in[4];
    const int* re   = (const int*)d_in[5];
    float* out      = (float*)d_out;

    bsattn_fused<<<dim3(512), dim3(512), 0, stream>>>(q, k, v, sc, rs, re, out);
}